// Round 16
// baseline (692.278 us; speedup 1.0000x reference)
//
#include <hip/hip_runtime.h>
#include <hip/hip_bf16.h>

// MambaSSM B=1,T=1024,H=S=256,L=4 — f32 in/out.
// Round 16: pre-split weights (bf16 hi/lo) + row-block MFMA GEMMs reading W
// direct from L2 + LN fused into W2 epilogue. 15 launches (was 18).

#define T_SEQ 1024
#define H_DIM 256

typedef __attribute__((ext_vector_type(8))) short short8;
typedef __attribute__((ext_vector_type(4))) float f32x4;

__device__ __forceinline__ float gelu_exact(float x) {
    return 0.5f * x * (1.0f + erff(x * 0.70710678118654752f));
}

__device__ __forceinline__ void split_bf16(float x, unsigned short& h, unsigned short& l) {
    __hip_bfloat16 bh = __float2bfloat16(x);          // RN
    float fh = __bfloat162float(bh);
    __hip_bfloat16 bl = __float2bfloat16(x - fh);
    __builtin_memcpy(&h, &bh, 2);
    __builtin_memcpy(&l, &bl, 2);
}

struct SplitArgs {
    const float* src[6];
    unsigned short* dh[6];
    unsigned short* dl[6];
    int n[6];
};

// One segment per blockIdx.y; grid-stride within segment.
__global__ __launch_bounds__(256) void presplit_kernel(SplitArgs a) {
    const int s = blockIdx.y;
    const float* __restrict__ src = a.src[s];
    unsigned short* __restrict__ dh = a.dh[s];
    unsigned short* __restrict__ dl = a.dl[s];
    const int n = a.n[s];
    for (int i = blockIdx.x * 256 + threadIdx.x; i < n; i += gridDim.x * 256) {
        unsigned short h, l;
        split_bf16(src[i], h, l);
        dh[i] = h; dl[i] = l;
    }
}

// Row-block GEMM: Y[M,N] = act(X[M,K] @ W[N,K]^T + bias) (+ dscale[n]*dmat[m,n])
// grid = M/32 blocks; block = 256 thr = 4 waves. Wave w owns cols
// [w*16*NTPW, ...+16*NTPW), 2 row-tiles of 16. N = 64*NTPW.
// W fragments read directly from pre-split global (L2-hot); only X staged.
// D layout: col=l&15, row=4*(l>>4)+j (m89-verified).
template<int NTPW, int ACT>
__global__ __launch_bounds__(256) void gemm_rb(
    const float* __restrict__ X,
    const unsigned short* __restrict__ Wh, const unsigned short* __restrict__ Wl,
    const float* __restrict__ bias, float* __restrict__ Y, int K,
    const float* __restrict__ dscale, const float* __restrict__ dmat)
{
    const int N = NTPW * 64;
    __shared__ unsigned short Xh[32][40], Xl[32][40];
    const int tid = threadIdx.x;
    const int lr = tid >> 3, lc = (tid & 7) * 4;
    const int wave = tid >> 6, lane = tid & 63;
    const int l15 = lane & 15, ko = lane >> 4;
    const int m0 = blockIdx.x * 32;
    const int ncb = wave * (NTPW * 16);

    f32x4 acc[2][NTPW];
#pragma unroll
    for (int r = 0; r < 2; ++r)
#pragma unroll
        for (int c = 0; c < NTPW; ++c) acc[r][c] = (f32x4){0.f, 0.f, 0.f, 0.f};

    for (int k0 = 0; k0 < K; k0 += 32) {
        const float4 xv = *reinterpret_cast<const float4*>(&X[(size_t)(m0 + lr) * K + k0 + lc]);
        ushort4 xh, xl;
        split_bf16(xv.x, xh.x, xl.x); split_bf16(xv.y, xh.y, xl.y);
        split_bf16(xv.z, xh.z, xl.z); split_bf16(xv.w, xh.w, xl.w);
        *reinterpret_cast<ushort4*>(&Xh[lr][lc]) = xh;
        *reinterpret_cast<ushort4*>(&Xl[lr][lc]) = xl;
        __syncthreads();

        short8 ah[2], al[2];
#pragma unroll
        for (int r = 0; r < 2; ++r) {
            ah[r] = *reinterpret_cast<const short8*>(&Xh[16 * r + l15][8 * ko]);
            al[r] = *reinterpret_cast<const short8*>(&Xl[16 * r + l15][8 * ko]);
        }
#pragma unroll
        for (int c = 0; c < NTPW; ++c) {
            const size_t woff = (size_t)(ncb + 16 * c + l15) * K + k0 + 8 * ko;
            const short8 bh = *reinterpret_cast<const short8*>(&Wh[woff]);
            const short8 bl = *reinterpret_cast<const short8*>(&Wl[woff]);
#pragma unroll
            for (int r = 0; r < 2; ++r) {
                acc[r][c] = __builtin_amdgcn_mfma_f32_16x16x32_bf16(ah[r], bh, acc[r][c], 0, 0, 0);
                acc[r][c] = __builtin_amdgcn_mfma_f32_16x16x32_bf16(ah[r], bl, acc[r][c], 0, 0, 0);
                acc[r][c] = __builtin_amdgcn_mfma_f32_16x16x32_bf16(al[r], bh, acc[r][c], 0, 0, 0);
            }
        }
        __syncthreads();
    }

#pragma unroll
    for (int c = 0; c < NTPW; ++c) {
        const int n_ = ncb + 16 * c + l15;
#pragma unroll
        for (int r = 0; r < 2; ++r)
#pragma unroll
            for (int j = 0; j < 4; ++j) {
                const int m_ = m0 + 16 * r + 4 * ko + j;
                float v = acc[r][c][j];
                if (bias)   v += bias[n_];
                if (dscale) v += dscale[n_] * dmat[(size_t)m_ * N + n_];
                if (ACT == 1) v = gelu_exact(v);
                Y[(size_t)m_ * N + n_] = v;
            }
    }
}

// W2 GEMM (N=256,K=512) with fused bias + LayerNorm + residual, h updated in place.
__global__ __launch_bounds__(256) void gemm_w2_ln(
    const float* __restrict__ Y1,
    const unsigned short* __restrict__ Wh, const unsigned short* __restrict__ Wl,
    const float* __restrict__ b2, const float* __restrict__ gamma,
    const float* __restrict__ beta, float* __restrict__ h)
{
    const int K = 512;
    __shared__ unsigned short Xh[32][40], Xl[32][40];
    __shared__ float yt[32][260];
    __shared__ float sred[32][8], s2red[32][8];
    __shared__ float mstat[32], istat[32];

    const int tid = threadIdx.x;
    const int lr = tid >> 3, lc = (tid & 7) * 4;
    const int wave = tid >> 6, lane = tid & 63;
    const int l15 = lane & 15, ko = lane >> 4;
    const int m0 = blockIdx.x * 32;

    f32x4 acc[2][4];
#pragma unroll
    for (int r = 0; r < 2; ++r)
#pragma unroll
        for (int c = 0; c < 4; ++c) acc[r][c] = (f32x4){0.f, 0.f, 0.f, 0.f};

    for (int k0 = 0; k0 < K; k0 += 32) {
        const float4 xv = *reinterpret_cast<const float4*>(&Y1[(size_t)(m0 + lr) * K + k0 + lc]);
        ushort4 xh, xl;
        split_bf16(xv.x, xh.x, xl.x); split_bf16(xv.y, xh.y, xl.y);
        split_bf16(xv.z, xh.z, xl.z); split_bf16(xv.w, xh.w, xl.w);
        *reinterpret_cast<ushort4*>(&Xh[lr][lc]) = xh;
        *reinterpret_cast<ushort4*>(&Xl[lr][lc]) = xl;
        __syncthreads();

        short8 ah[2], al[2];
#pragma unroll
        for (int r = 0; r < 2; ++r) {
            ah[r] = *reinterpret_cast<const short8*>(&Xh[16 * r + l15][8 * ko]);
            al[r] = *reinterpret_cast<const short8*>(&Xl[16 * r + l15][8 * ko]);
        }
#pragma unroll
        for (int c = 0; c < 4; ++c) {
            const size_t woff = (size_t)(wave * 64 + 16 * c + l15) * K + k0 + 8 * ko;
            const short8 bh = *reinterpret_cast<const short8*>(&Wh[woff]);
            const short8 bl = *reinterpret_cast<const short8*>(&Wl[woff]);
#pragma unroll
            for (int r = 0; r < 2; ++r) {
                acc[r][c] = __builtin_amdgcn_mfma_f32_16x16x32_bf16(ah[r], bh, acc[r][c], 0, 0, 0);
                acc[r][c] = __builtin_amdgcn_mfma_f32_16x16x32_bf16(ah[r], bl, acc[r][c], 0, 0, 0);
                acc[r][c] = __builtin_amdgcn_mfma_f32_16x16x32_bf16(al[r], bh, acc[r][c], 0, 0, 0);
            }
        }
        __syncthreads();
    }

    // acc (+bias) -> LDS row-major y tile
#pragma unroll
    for (int c = 0; c < 4; ++c) {
        const int n_ = wave * 64 + 16 * c + l15;
        const float bv = b2[n_];
#pragma unroll
        for (int r = 0; r < 2; ++r)
#pragma unroll
            for (int j = 0; j < 4; ++j)
                yt[16 * r + 4 * ko + j][n_] = acc[r][c][j] + bv;
    }
    __syncthreads();

    // row partial sums (8 threads per row)
    {
        const int r = tid >> 3, g = tid & 7;
        float s = 0.f, s2 = 0.f;
#pragma unroll
        for (int i = 0; i < 32; ++i) {
            const float v = yt[r][g * 32 + i];
            s += v; s2 += v * v;
        }
        sred[r][g] = s; s2red[r][g] = s2;
    }
    __syncthreads();
    if (tid < 32) {
        float s = 0.f, s2 = 0.f;
#pragma unroll
        for (int g = 0; g < 8; ++g) { s += sred[tid][g]; s2 += s2red[tid][g]; }
        const float mean = s * (1.0f / H_DIM);
        const float var  = s2 * (1.0f / H_DIM) - mean * mean;
        mstat[tid] = mean;
        istat[tid] = rsqrtf(var + 1e-5f);
    }
    __syncthreads();

    // h = LN(y)*gamma+beta + h
    {
        const int r = tid >> 3, g = tid & 7;
        const float mean = mstat[r], inv = istat[r];
        const int m_ = m0 + r;
#pragma unroll
        for (int i0 = 0; i0 < 32; i0 += 4) {
            const int c = g * 32 + i0;
            const float4 hv = *reinterpret_cast<const float4*>(&h[(size_t)m_ * H_DIM + c]);
            const float4 gv = *reinterpret_cast<const float4*>(&gamma[c]);
            const float4 bv = *reinterpret_cast<const float4*>(&beta[c]);
            float4 o;
            o.x = (yt[r][c + 0] - mean) * inv * gv.x + bv.x + hv.x;
            o.y = (yt[r][c + 1] - mean) * inv * gv.y + bv.y + hv.y;
            o.z = (yt[r][c + 2] - mean) * inv * gv.z + bv.z + hv.z;
            o.w = (yt[r][c + 3] - mean) * inv * gv.w + bv.w + hv.w;
            *reinterpret_cast<float4*>(&h[(size_t)m_ * H_DIM + c]) = o;
        }
    }
}

// Parallel scan: v_t = a_t*v_{t-1} + b_t, a_0=0, b_0=h_0. 4 blocks x 1024 thr.
__global__ __launch_bounds__(1024) void scan_par(
    const float* __restrict__ dtpre, const float* __restrict__ h,
    float* __restrict__ vs)
{
    __shared__ float sA[16][64], sB[16][64];
    const int chl   = threadIdx.x & 63;
    const int chunk = threadIdx.x >> 6;
    const int c  = blockIdx.x * 64 + chl;
    const int t0 = chunk * 64;

    float A = 1.f, B = 0.f;
    for (int i = 0; i < 64; ++i) {
        const int t = t0 + i;
        const float hv = h[(size_t)t * H_DIM + c];
        float a, b;
        if (t == 0) { a = 0.f; b = hv; }
        else {
            const float dt = 1.0f / (1.0f + __expf(-dtpre[(size_t)t * H_DIM + c]));
            a = dt; b = (1.0f - dt) * hv;
        }
        A = a * A;
        B = fmaf(a, B, b);
    }
    sA[chunk][chl] = A; sB[chunk][chl] = B;
    __syncthreads();

    if (chunk == 0) {
        float pA = 1.f, pB = 0.f;
        for (int j = 0; j < 16; ++j) {
            const float cA = sA[j][chl], cB = sB[j][chl];
            sA[j][chl] = pA; sB[j][chl] = pB;
            pA = cA * pA;
            pB = fmaf(cA, pB, cB);
        }
    }
    __syncthreads();

    A = sA[chunk][chl]; B = sB[chunk][chl];
    for (int i = 0; i < 64; ++i) {
        const int t = t0 + i;
        const float hv = h[(size_t)t * H_DIM + c];
        float a, b;
        if (t == 0) { a = 0.f; b = hv; }
        else {
            const float dt = 1.0f / (1.0f + __expf(-dtpre[(size_t)t * H_DIM + c]));
            a = dt; b = (1.0f - dt) * hv;
        }
        A = a * A;
        B = fmaf(a, B, b);
        vs[(size_t)t * H_DIM + c] = B;
    }
}

// out rows (f32): row0 = src[0] once; i>=1: 256 copies of src[i] at 1+(i-1)*256.
__global__ __launch_bounds__(256) void replicate_f32(
    const float* __restrict__ src, float* __restrict__ out)
{
    const int i = blockIdx.x;
    const int tid = threadIdx.x;
    const int cg = tid & 63;
    const int sub = tid >> 6;

    const float4 v = *reinterpret_cast<const float4*>(&src[(size_t)i * H_DIM + cg * 4]);

    if (i == 0) {
        if (blockIdx.y == 0 && sub == 0)
            *reinterpret_cast<float4*>(&out[(size_t)cg * 4]) = v;
    } else {
        const size_t base = (size_t)(1 + (i - 1) * H_DIM + blockIdx.y * 64) * H_DIM;
#pragma unroll 4
        for (int it = 0; it < 16; ++it) {
            const size_t row_off = base + (size_t)(sub + it * 4) * H_DIM;
            *reinterpret_cast<float4*>(&out[row_off + cg * 4]) = v;
        }
    }
}

extern "C" void kernel_launch(void* const* d_in, const int* in_sizes, int n_in,
                              void* d_out, int out_size, void* d_ws, size_t ws_size,
                              hipStream_t stream)
{
    const float* x     = (const float*)d_in[0];
    const float* W_in  = (const float*)d_in[1];
    const float* b_in  = (const float*)d_in[2];
    const float* W1    = (const float*)d_in[3];
    const float* b1    = (const float*)d_in[4];
    const float* W2    = (const float*)d_in[5];
    const float* b2    = (const float*)d_in[6];
    const float* gamma = (const float*)d_in[7];
    const float* beta  = (const float*)d_in[8];
    const float* W_dt  = (const float*)d_in[9];
    const float* b_dt  = (const float*)d_in[10];
    const float* C     = (const float*)d_in[11];
    const float* D     = (const float*)d_in[12];
    const float* W_out = (const float*)d_in[13];
    const float* b_out = (const float*)d_in[14];
    float* out = (float*)d_out;

    float* ws    = (float*)d_ws;
    float* h     = ws;                  // 262144
    float* y1    = ws + 262144;         // 524288
    float* dtpre = ws + 786432;         // 262144
    float* vs    = ws + 1048576;        // 262144
    float* u     = ws + 1310720;        // 262144
    float* ou    = ws + 1572864;        // 262144
    unsigned short* wsh = (unsigned short*)(ws + 1835008);   // split weights

    unsigned short* Whin = wsh;               unsigned short* Wlin = wsh + 65536;
    unsigned short* Wh1  = wsh + 131072;      unsigned short* Wl1  = wsh + 655360;
    unsigned short* Wh2  = wsh + 1179648;     unsigned short* Wl2  = wsh + 1703936;
    unsigned short* Whdt = wsh + 2228224;     unsigned short* Wldt = wsh + 2293760;
    unsigned short* WhC  = wsh + 2359296;     unsigned short* WlC  = wsh + 2424832;
    unsigned short* Whout= wsh + 2490368;     unsigned short* Wlout= wsh + 2555904;

    SplitArgs sa;
    sa.src[0] = W_in;  sa.dh[0] = Whin;  sa.dl[0] = Wlin;  sa.n[0] = 65536;
    sa.src[1] = W1;    sa.dh[1] = Wh1;   sa.dl[1] = Wl1;   sa.n[1] = 524288;
    sa.src[2] = W2;    sa.dh[2] = Wh2;   sa.dl[2] = Wl2;   sa.n[2] = 524288;
    sa.src[3] = W_dt;  sa.dh[3] = Whdt;  sa.dl[3] = Wldt;  sa.n[3] = 65536;
    sa.src[4] = C;     sa.dh[4] = WhC;   sa.dl[4] = WlC;   sa.n[4] = 65536;
    sa.src[5] = W_out; sa.dh[5] = Whout; sa.dl[5] = Wlout; sa.n[5] = 65536;

    const dim3 blk(256);

    presplit_kernel<<<dim3(256, 6), blk, 0, stream>>>(sa);

    // h = x @ W_in^T + b_in
    gemm_rb<4, 0><<<dim3(32), blk, 0, stream>>>(
        x, Whin, Wlin, b_in, h, H_DIM, nullptr, nullptr);

    for (int l = 0; l < 4; ++l) {
        // y1 = gelu(h @ W1[l]^T + b1[l])
        gemm_rb<8, 1><<<dim3(32), blk, 0, stream>>>(
            h, Wh1 + (size_t)l * 131072, Wl1 + (size_t)l * 131072,
            b1 + l * 512, y1, H_DIM, nullptr, nullptr);
        // h = LN(y1 @ W2[l]^T + b2[l]) * gamma + beta + h
        gemm_w2_ln<<<dim3(32), blk, 0, stream>>>(
            y1, Wh2 + (size_t)l * 131072, Wl2 + (size_t)l * 131072,
            b2 + l * 256, gamma + l * 256, beta + l * 256, h);
    }

    // dtpre = h @ W_dt^T + b_dt
    gemm_rb<4, 0><<<dim3(32), blk, 0, stream>>>(
        h, Whdt, Wldt, b_dt, dtpre, H_DIM, nullptr, nullptr);

    // scan -> vs
    scan_par<<<dim3(H_DIM / 64), dim3(1024), 0, stream>>>(dtpre, h, vs);

    // u = vs @ C^T + D*h
    gemm_rb<4, 0><<<dim3(32), blk, 0, stream>>>(
        vs, WhC, WlC, nullptr, u, H_DIM, D, h);

    // ou = u @ W_out^T + b_out
    gemm_rb<4, 0><<<dim3(32), blk, 0, stream>>>(
        u, Whout, Wlout, b_out, ou, H_DIM, nullptr, nullptr);

    // replicate -> f32 out
    replicate_f32<<<dim3(T_SEQ, 4), blk, 0, stream>>>(ou, out);
}